// Round 6
// baseline (324.297 us; speedup 1.0000x reference)
//
#include <hip/hip_runtime.h>
#include <math.h>

// Problem dims: B=8, N=512, T=64, D=128, E=32, M=3, BN=4096
// ws layout (float offsets) — only these regions are used now:
#define OFF_H      13056      // 4096*128
#define OFF_HV     537376     // 4096
#define OFF_SCORES 541472     // 768*512
#define OFF_HMIX   934688     // 8*32*512

typedef short bf16x8 __attribute__((ext_vector_type(8)));
typedef float f32x4 __attribute__((ext_vector_type(4)));

union U8 { unsigned short s[8]; bf16x8 v; uint4 u4; };

__device__ __forceinline__ unsigned short bf16_rtn(float f) {
  unsigned int u = __float_as_uint(f);
  return (unsigned short)((u + 0x7FFFu + ((u >> 16) & 1u)) >> 16);
}
__device__ __forceinline__ float bf16_f(unsigned short h) {
  return __uint_as_float(((unsigned int)h) << 16);
}
// RTN split of 8 floats into hi/lo bf16x8 (for weights)
__device__ __forceinline__ void split8_rtn(const float* v, bf16x8* hi, bf16x8* lo) {
  U8 a, b;
#pragma unroll
  for (int j = 0; j < 8; ++j) {
    unsigned short h = bf16_rtn(v[j]);
    a.s[j] = h;
    b.s[j] = bf16_rtn(v[j] - bf16_f(h));
  }
  *hi = a.v; *lo = b.v;
}

// ---------------------------------------------------------------------------
// GRU: 256 blocks x 512 threads, 16 seqs/block. Fully self-contained:
// W_hh fragments converted in-block from fp32, u/c dots in-block,
// Hmix slice zeroed here. 3 MFMA acc chains; trunc-hi/RTN-lo h split.
// ---------------------------------------------------------------------------
__global__ __launch_bounds__(512, 2) void gru_kernel(const float* __restrict__ x,
                                                     const float* __restrict__ Wih,
                                                     const float* __restrict__ projW,
                                                     const float* __restrict__ projb,
                                                     const float* __restrict__ bih,
                                                     const float* __restrict__ Whh,
                                                     const float* __restrict__ bhh,
                                                     const float* __restrict__ outW,
                                                     float* __restrict__ ws) {
  __shared__ __align__(16) unsigned short hHi[2][16 * 17 * 8];
  __shared__ __align__(16) unsigned short hLo[2][16 * 17 * 8];
  __shared__ float xsAll[16 * 65];
  __shared__ float hFin[16 * 132];

  const int tid = threadIdx.x, wave = tid >> 6, lane = tid & 63;
  const int q = lane >> 4, s15 = lane & 15;
  const int d = wave * 16 + s15;

  // zero this block's Hmix slice (512 floats)
  {
    float4 z4 = make_float4(0.f, 0.f, 0.f, 0.f);
    float4* hm4 = (float4*)(ws + OFF_HMIX);
    if (tid < 128) hm4[blockIdx.x * 128 + tid] = z4;
  }

  // W_hh B-fragments (split bf16) from global fp32
  bf16x8 Bhi[3][4], Blo[3][4];
#pragma unroll
  for (int t = 0; t < 3; ++t) {
    int row = (wave + 8 * t) * 16 + s15;
#pragma unroll
    for (int c = 0; c < 4; ++c) {
      float v[8];
      *(float4*)v = *(const float4*)&Whh[row * 128 + c * 32 + q * 8];
      *(float4*)(v + 4) = *(const float4*)&Whh[row * 128 + c * 32 + q * 8 + 4];
      split8_rtn(v, &Bhi[t][c], &Blo[t][c]);
    }
  }

  // u/c per-lane constants: u = Wih@projW, p = Wih@projb (rows d, 128+d, 256+d)
  float ur = 0.f, uz = 0.f, un = 0.f, pr0 = 0.f, pz0 = 0.f, pn0 = 0.f;
  for (int k = 0; k < 128; k += 4) {
    float4 w0 = *(const float4*)&Wih[d * 128 + k];
    float4 w1 = *(const float4*)&Wih[(128 + d) * 128 + k];
    float4 w2 = *(const float4*)&Wih[(256 + d) * 128 + k];
    float4 pw = *(const float4*)&projW[k];
    float4 pb = *(const float4*)&projb[k];
    ur += w0.x * pw.x + w0.y * pw.y + w0.z * pw.z + w0.w * pw.w;
    uz += w1.x * pw.x + w1.y * pw.y + w1.z * pw.z + w1.w * pw.w;
    un += w2.x * pw.x + w2.y * pw.y + w2.z * pw.z + w2.w * pw.w;
    pr0 += w0.x * pb.x + w0.y * pb.y + w0.z * pb.z + w0.w * pb.w;
    pz0 += w1.x * pb.x + w1.y * pb.y + w1.z * pb.z + w1.w * pb.w;
    pn0 += w2.x * pb.x + w2.y * pb.y + w2.z * pb.z + w2.w * pb.w;
  }
  const float cr = pr0 + bih[d] + bhh[d];
  const float cz = pz0 + bih[128 + d] + bhh[128 + d];
  const float cn = pn0 + bih[256 + d];
  const float bj2 = bhh[256 + d];

  const int seq0 = blockIdx.x * 16;
  for (int i = tid; i < 1024; i += 512) {
    int s = i >> 6, tt = i & 63;
    int r = (seq0 + s) * 64 + tt;
    xsAll[s * 65 + tt] = x[((r >> 15) * 512 + (r & 511)) * 64 + ((r >> 9) & 63)];
  }
  for (int i = tid; i < 2176; i += 512) { hHi[0][i] = 0; hLo[0][i] = 0; }
  __syncthreads();

  float hreg[4] = {0.f, 0.f, 0.f, 0.f};
  const int g = d >> 3, e = d & 7;

  for (int t = 0; t < 64; ++t) {
    const int rb = t & 1, wb = rb ^ 1;
    f32x4 acc0 = {0.f, 0.f, 0.f, 0.f};
    f32x4 acc1 = {0.f, 0.f, 0.f, 0.f};
    f32x4 acc2 = {0.f, 0.f, 0.f, 0.f};
#pragma unroll
    for (int c = 0; c < 4; ++c) {
      bf16x8 Ahi = *(const bf16x8*)&hHi[rb][((c * 4 + q) * 17 + s15) * 8];
      bf16x8 Alo = *(const bf16x8*)&hLo[rb][((c * 4 + q) * 17 + s15) * 8];
      acc0 = __builtin_amdgcn_mfma_f32_16x16x32_bf16(Ahi, Bhi[0][c], acc0, 0, 0, 0);
      acc1 = __builtin_amdgcn_mfma_f32_16x16x32_bf16(Ahi, Bhi[1][c], acc1, 0, 0, 0);
      acc2 = __builtin_amdgcn_mfma_f32_16x16x32_bf16(Ahi, Bhi[2][c], acc2, 0, 0, 0);
      acc0 = __builtin_amdgcn_mfma_f32_16x16x32_bf16(Alo, Bhi[0][c], acc0, 0, 0, 0);
      acc1 = __builtin_amdgcn_mfma_f32_16x16x32_bf16(Alo, Bhi[1][c], acc1, 0, 0, 0);
      acc2 = __builtin_amdgcn_mfma_f32_16x16x32_bf16(Alo, Bhi[2][c], acc2, 0, 0, 0);
      acc0 = __builtin_amdgcn_mfma_f32_16x16x32_bf16(Ahi, Blo[0][c], acc0, 0, 0, 0);
      acc1 = __builtin_amdgcn_mfma_f32_16x16x32_bf16(Ahi, Blo[1][c], acc1, 0, 0, 0);
      acc2 = __builtin_amdgcn_mfma_f32_16x16x32_bf16(Ahi, Blo[2][c], acc2, 0, 0, 0);
    }
    float xsv[4];
#pragma unroll
    for (int r = 0; r < 4; ++r) xsv[r] = xsAll[(q * 4 + r) * 65 + t];
#pragma unroll
    for (int r = 0; r < 4; ++r) {
      int s = q * 4 + r;
      float gr = fmaf(xsv[r], ur, cr + acc0[r]);
      float gz = fmaf(xsv[r], uz, cz + acc1[r]);
      float gn = fmaf(xsv[r], un, cn);
      float hn = acc2[r] + bj2;
      float rr = __builtin_amdgcn_rcpf(1.f + __expf(-gr));
      float zz = 1.f - __builtin_amdgcn_rcpf(1.f + __expf(-gz));  // 1-z
      float a = fmaf(rr, hn, gn);
      float ng = 1.f - 2.f * __builtin_amdgcn_rcpf(__expf(2.f * a) + 1.f);
      float hv = fmaf(zz, ng - hreg[r], hreg[r]);
      hreg[r] = hv;
      unsigned int u = __float_as_uint(hv);
      unsigned short hi = (unsigned short)(u >> 16);                 // trunc-hi
      unsigned short lo = bf16_rtn(hv - __uint_as_float(u & 0xFFFF0000u));
      int idx = (g * 17 + s) * 8 + e;
      hHi[wb][idx] = hi;
      hLo[wb][idx] = lo;
    }
    __syncthreads();
  }

  // final h -> LDS staging, then global + hv
#pragma unroll
  for (int r = 0; r < 4; ++r) hFin[(q * 4 + r) * 132 + d] = hreg[r];
  __syncthreads();
  float* h_out = ws + OFF_H;
#pragma unroll
  for (int p = 0; p < 4; ++p) {
    int item = tid + p * 512;
    int s = item >> 7, dd = item & 127;
    h_out[(seq0 + s) * 128 + dd] = hFin[s * 132 + dd];
  }
  for (int s = wave * 2; s < wave * 2 + 2; ++s) {
    float a = hFin[s * 132 + lane] * outW[lane] + hFin[s * 132 + 64 + lane] * outW[64 + lane];
    for (int off = 32; off; off >>= 1) a += __shfl_xor(a, off);
    if (lane == 0) ws[OFF_HV + seq0 + s] = a;
  }
}

// ---------------------------------------------------------------------------
// Fused stats+router+scores+topk: 24 blocks (b,m) x 512 threads (8 waves).
// scores = (QW@h + qb)/||W@h + sb|| with QW = qn@W (in-block), reusing the
// same h A-fragments for both matmuls. topk reads back the block's own
// global score writes (visible after __syncthreads) and scatters into Hmix.
// ---------------------------------------------------------------------------
__global__ __launch_bounds__(512) void scoretopk_kernel(const float* __restrict__ spaceW,
                                                        const float* __restrict__ spaceb,
                                                        const float* __restrict__ queries,
                                                        const float* __restrict__ routerW,
                                                        const float* __restrict__ routerb,
                                                        float* __restrict__ ws,
                                                        float* __restrict__ d_out) {
  const int bid = blockIdx.x;
  const int b = bid / 3, m = bid % 3;
  const int tid = threadIdx.x, wave = tid >> 6, lane = tid & 63;
  const int q = lane >> 4, s15 = lane & 15;

  __shared__ __align__(16) unsigned short sHi[16 * 33 * 8];
  __shared__ __align__(16) unsigned short sLo[16 * 33 * 8];
  __shared__ __align__(16) unsigned short qwHi[32 * 128];
  __shared__ __align__(16) unsigned short qwLo[32 * 128];
  __shared__ float hsL[128 * 36];
  __shared__ float redA[512], redB[512];
  __shared__ float st[256];
  __shared__ float invnL[32], invqL[32], qbL[32];
  __shared__ float lgS[3];
  __shared__ float probsS;

  const float* h = ws + OFF_H;

  // ---- phase 0a: stats partials ----
  {
    int dd = tid & 127, p = tid >> 7;
    float sum = 0.f, sq = 0.f;
    for (int i = 0; i < 128; ++i) {
      float v = h[(b * 512 + p * 128 + i) * 128 + dd];
      sum += v; sq += v * v;
    }
    redA[p * 128 + dd] = sum;
    redB[p * 128 + dd] = sq;
  }
  // ---- phase 0b: query inverse norms (4 rows per wave) ----
#pragma unroll
  for (int i = 0; i < 4; ++i) {
    int e = wave * 4 + i;
    float v0 = queries[(m * 32 + e) * 128 + lane];
    float v1 = queries[(m * 32 + e) * 128 + 64 + lane];
    float ss = v0 * v0 + v1 * v1;
    for (int off = 32; off; off >>= 1) ss += __shfl_xor(ss, off);
    if (lane == 0) invqL[e] = 1.f / fmaxf(sqrtf(ss), 1e-12f);
  }
  __syncthreads();
  if (tid < 128) {
    float s = redA[tid] + redA[128 + tid] + redA[256 + tid] + redA[384 + tid];
    float q2 = redB[tid] + redB[128 + tid] + redB[256 + tid] + redB[384 + tid];
    float mean = s * (1.f / 512.f);
    float var = (q2 - 512.f * mean * mean) * (1.f / 511.f);  // ddof=1
    st[tid] = mean;
    st[128 + tid] = sqrtf(fmaxf(var, 0.f));
  }
  if (tid >= 256 && tid < 288) {   // qb (uses invqL, not st)
    int e = tid - 256;
    float acc = 0.f;
    for (int dd = 0; dd < 128; ++dd)
      acc += queries[(m * 32 + e) * 128 + dd] * spaceb[m * 128 + dd];
    qbL[e] = acc * invqL[e];
  }
  __syncthreads();
  if (tid < 3) {
    float acc = routerb[tid];
    for (int k = 0; k < 256; ++k) acc += st[k] * routerW[tid * 256 + k];
    lgS[tid] = acc;
  }
  __syncthreads();
  if (tid == 0) {
    float mx = fmaxf(lgS[0], fmaxf(lgS[1], lgS[2]));
    float e0 = expf(lgS[0] - mx), e1 = expf(lgS[1] - mx), e2 = expf(lgS[2] - mx);
    float inv = 1.f / (e0 + e1 + e2);
    probsS = (m == 0) ? e0 * inv : ((m == 1) ? e1 * inv : e2 * inv);
    if (m == 0) {
      d_out[4096 + b * 3 + 0] = e0 * inv;
      d_out[4096 + b * 3 + 1] = e1 * inv;
      d_out[4096 + b * 3 + 2] = e2 * inv;
    }
  }
  // ---- phase 0c: QW = qn @ spaceW[m]  (32e x 128k), split to bf16 LDS ----
  {
    int e = tid >> 4, k0 = (tid & 15) * 8;
    float acc[8] = {0.f, 0.f, 0.f, 0.f, 0.f, 0.f, 0.f, 0.f};
    float inv = invqL[e];
    for (int dd = 0; dd < 128; ++dd) {
      float qv = queries[(m * 32 + e) * 128 + dd] * inv;
      const float* wr = &spaceW[m * 16384 + dd * 128 + k0];
      float4 wa = *(const float4*)wr;
      float4 wb = *(const float4*)(wr + 4);
      acc[0] += qv * wa.x; acc[1] += qv * wa.y; acc[2] += qv * wa.z; acc[3] += qv * wa.w;
      acc[4] += qv * wb.x; acc[5] += qv * wb.y; acc[6] += qv * wb.z; acc[7] += qv * wb.w;
    }
#pragma unroll
    for (int j = 0; j < 8; ++j) {
      unsigned short hi = bf16_rtn(acc[j]);
      qwHi[e * 128 + k0 + j] = hi;
      qwLo[e * 128 + k0 + j] = bf16_rtn(acc[j] - bf16_f(hi));
    }
  }
  __syncthreads();

  // persistent B-fragments: wave -> nt = wave>>2, d-tiles {wave&3, (wave&3)+4}
  const int dtA = wave & 3, dtB = dtA + 4, nt = wave >> 2;
  const bool isSc = (dtA < 2);
  const int et = dtA;  // score e-tile for score waves
  bf16x8 WAhi[4], WAlo[4], WBhi[4], WBlo[4], Qhi[4], Qlo[4];
#pragma unroll
  for (int c = 0; c < 4; ++c) {
    float v[8];
    const float* ra = &spaceW[m * 16384 + (dtA * 16 + s15) * 128 + c * 32 + q * 8];
    *(float4*)v = *(const float4*)ra; *(float4*)(v + 4) = *(const float4*)(ra + 4);
    split8_rtn(v, &WAhi[c], &WAlo[c]);
    const float* rb2 = &spaceW[m * 16384 + (dtB * 16 + s15) * 128 + c * 32 + q * 8];
    *(float4*)v = *(const float4*)rb2; *(float4*)(v + 4) = *(const float4*)(rb2 + 4);
    split8_rtn(v, &WBhi[c], &WBlo[c]);
    if (isSc) {
      Qhi[c] = *(const bf16x8*)&qwHi[(et * 16 + s15) * 128 + c * 32 + q * 8];
      Qlo[c] = *(const bf16x8*)&qwLo[(et * 16 + s15) * 128 + c * 32 + q * 8];
    }
  }
  const float sbA = spaceb[m * 128 + dtA * 16 + s15];
  const float sbB = spaceb[m * 128 + dtB * 16 + s15];

  // ---- phase 1: 16 slabs of 32 n ----
  for (int sl = 0; sl < 16; ++sl) {
    int n0 = sl * 32;
    {  // stage h slab as split bf16 A-fragments (one full 8-elem cell/thread)
      int nn = tid >> 4, gc = tid & 15;
      const float* hp = &h[(b * 512 + n0 + nn) * 128 + gc * 8];
      float v[8];
      *(float4*)v = *(const float4*)hp;
      *(float4*)(v + 4) = *(const float4*)(hp + 4);
      U8 ph, pl;
#pragma unroll
      for (int j = 0; j < 8; ++j) {
        unsigned int u = __float_as_uint(v[j]);
        ph.s[j] = (unsigned short)(u >> 16);
        pl.s[j] = bf16_rtn(v[j] - __uint_as_float(u & 0xFFFF0000u));
      }
      *(uint4*)&sHi[(gc * 33 + nn) * 8] = ph.u4;
      *(uint4*)&sLo[(gc * 33 + nn) * 8] = pl.u4;
    }
    __syncthreads();
    bf16x8 Ahi[4], Alo[4];
#pragma unroll
    for (int c = 0; c < 4; ++c) {
      Ahi[c] = *(const bf16x8*)&sHi[((c * 4 + q) * 33 + nt * 16 + s15) * 8];
      Alo[c] = *(const bf16x8*)&sLo[((c * 4 + q) * 33 + nt * 16 + s15) * 8];
    }
    f32x4 aA = {0.f, 0.f, 0.f, 0.f};
    f32x4 aB = {0.f, 0.f, 0.f, 0.f};
    f32x4 aS = {0.f, 0.f, 0.f, 0.f};
#pragma unroll
    for (int c = 0; c < 4; ++c) {
      aA = __builtin_amdgcn_mfma_f32_16x16x32_bf16(Ahi[c], WAhi[c], aA, 0, 0, 0);
      aA = __builtin_amdgcn_mfma_f32_16x16x32_bf16(Alo[c], WAhi[c], aA, 0, 0, 0);
      aA = __builtin_amdgcn_mfma_f32_16x16x32_bf16(Ahi[c], WAlo[c], aA, 0, 0, 0);
      aB = __builtin_amdgcn_mfma_f32_16x16x32_bf16(Ahi[c], WBhi[c], aB, 0, 0, 0);
      aB = __builtin_amdgcn_mfma_f32_16x16x32_bf16(Alo[c], WBhi[c], aB, 0, 0, 0);
      aB = __builtin_amdgcn_mfma_f32_16x16x32_bf16(Ahi[c], WBlo[c], aB, 0, 0, 0);
      if (isSc) {
        aS = __builtin_amdgcn_mfma_f32_16x16x32_bf16(Ahi[c], Qhi[c], aS, 0, 0, 0);
        aS = __builtin_amdgcn_mfma_f32_16x16x32_bf16(Alo[c], Qhi[c], aS, 0, 0, 0);
        aS = __builtin_amdgcn_mfma_f32_16x16x32_bf16(Ahi[c], Qlo[c], aS, 0, 0, 0);
      }
    }
    // hs tiles -> hsL[d][n] (for norms only)
    {
      float4 oa = make_float4(aA[0] + sbA, aA[1] + sbA, aA[2] + sbA, aA[3] + sbA);
      float4 ob = make_float4(aB[0] + sbB, aB[1] + sbB, aB[2] + sbB, aB[3] + sbB);
      *(float4*)&hsL[(dtA * 16 + s15) * 36 + nt * 16 + q * 4] = oa;
      *(float4*)&hsL[(dtB * 16 + s15) * 36 + nt * 16 + q * 4] = ob;
    }
    __syncthreads();
    {  // norm partials: 32 n x 16 d-parts
      int n = tid & 31, dp = tid >> 5;
      float ss = 0.f;
#pragma unroll
      for (int j = 0; j < 8; ++j) {
        float v = hsL[(dp * 8 + j) * 36 + n];
        ss += v * v;
      }
      redA[dp * 32 + n] = ss;
    }
    __syncthreads();
    if (tid < 32) {
      float ss = 0.f;
#pragma unroll
      for (int j = 0; j < 16; ++j) ss += redA[j * 32 + tid];
      invnL[tid] = 1.f / fmaxf(sqrtf(ss), 1e-12f);
    }
    __syncthreads();
    if (isSc) {
      int nb = nt * 16 + q * 4;
      float qb = qbL[et * 16 + s15];
      float4 o;
      o.x = (aS[0] + qb) * invnL[nb + 0];
      o.y = (aS[1] + qb) * invnL[nb + 1];
      o.z = (aS[2] + qb) * invnL[nb + 2];
      o.w = (aS[3] + qb) * invnL[nb + 3];
      *(float4*)&ws[OFF_SCORES + ((b * 3 + m) * 32 + et * 16 + s15) * 512 + n0 + nb] = o;
    }
    __syncthreads();
  }

  // ---- phase 2: topk (4 e-rows per wave) ----
  float prob = probsS;
  for (int rr = 0; rr < 4; ++rr) {
    int e = wave * 4 + rr;
    const float* sc = ws + OFF_SCORES + ((b * 3 + m) * 32 + e) * 512;
    float v[8];
#pragma unroll
    for (int j = 0; j < 8; ++j) v[j] = sc[j * 64 + lane];
    float selv = 0.f; int seli = 0; float maxv = 0.f;
    for (int it = 0; it < 25; ++it) {
      float bv = v[0]; int bj = 0;
#pragma unroll
      for (int j = 1; j < 8; ++j)
        if (v[j] > bv) { bv = v[j]; bj = j; }
      int bidx = bj * 64 + lane;
      for (int off = 32; off; off >>= 1) {
        float ov = __shfl_xor(bv, off);
        int oi = __shfl_xor(bidx, off);
        if (ov > bv || (ov == bv && oi < bidx)) { bv = ov; bidx = oi; }
      }
      if (lane == (bidx & 63)) v[bidx >> 6] = -INFINITY;
      if (it == 0) maxv = bv;
      if (lane == it) { selv = bv; seli = bidx; }
    }
    float ex = (lane < 25) ? __expf((selv - maxv) * (1.f / 0.7f)) : 0.f;
    float den = ex;
    for (int off = 32; off; off >>= 1) den += __shfl_xor(den, off);
    if (lane < 25)
      atomicAdd(&ws[OFF_HMIX + (b * 32 + e) * 512 + seli], prob * ex / den);
  }
}

// ---------------------------------------------------------------------------
// ev + final fused: 64 blocks (b, 64-n chunk) x 256 threads. ev recomputed
// per block (trivial), then output rows.
// ---------------------------------------------------------------------------
__global__ __launch_bounds__(256) void evfinal_kernel(const float* __restrict__ prior,
                                                      const float* __restrict__ outb,
                                                      const float* __restrict__ plog,
                                                      float* __restrict__ ws,
                                                      float* __restrict__ d_out) {
  const int bid = blockIdx.x;
  const int b = bid >> 3, ch = bid & 7;
  const int tid = threadIdx.x, wave = tid >> 6, lane = tid & 63;
  __shared__ float hvL[512], evL[32];
  for (int i = tid; i < 512; i += 256) hvL[i] = ws[OFF_HV + b * 512 + i];
  __syncthreads();
#pragma unroll
  for (int i = 0; i < 8; ++i) {
    int e = wave * 8 + i;
    const float* Hm = ws + OFF_HMIX + (b * 32 + e) * 512;
    float a = 0.f;
#pragma unroll
    for (int j = 0; j < 8; ++j) a += Hm[j * 64 + lane] * hvL[j * 64 + lane];
    for (int off = 32; off; off >>= 1) a += __shfl_xor(a, off);
    if (lane == 0) evL[e] = a;
  }
  __syncthreads();
  float alpha = 1.f / (1.f + expf(-plog[0]));
  float ob = outb[0];
  for (int i = 0; i < 16; ++i) {
    int n = ch * 64 + wave * 16 + i;
    const float* pr = prior + n * 512;
    float s1 = 0.f;
#pragma unroll
    for (int j = 0; j < 8; ++j) s1 += pr[j * 64 + lane] * hvL[j * 64 + lane];
    float s2 = 0.f;
    if (lane < 32) s2 = ws[OFF_HMIX + (b * 32 + lane) * 512 + n] * evL[lane];
    float a = alpha * s1 + (1.f - alpha) * s2;
    for (int off = 32; off; off >>= 1) a += __shfl_xor(a, off);
    if (lane == 0) d_out[b * 512 + n] = a + ob;
  }
}

// ---------------------------------------------------------------------------
extern "C" void kernel_launch(void* const* d_in, const int* in_sizes, int n_in,
                              void* d_out, int out_size, void* d_ws, size_t ws_size,
                              hipStream_t stream) {
  const float* x       = (const float*)d_in[0];
  const float* prior   = (const float*)d_in[1];
  const float* projW   = (const float*)d_in[2];
  const float* projb   = (const float*)d_in[3];
  const float* Wih     = (const float*)d_in[4];
  const float* Whh     = (const float*)d_in[5];
  const float* bih     = (const float*)d_in[6];
  const float* bhh     = (const float*)d_in[7];
  const float* spaceW  = (const float*)d_in[8];
  const float* spaceb  = (const float*)d_in[9];
  const float* routerW = (const float*)d_in[10];
  const float* routerb = (const float*)d_in[11];
  const float* outW    = (const float*)d_in[12];
  const float* outb    = (const float*)d_in[13];
  const float* plog    = (const float*)d_in[14];
  const float* queries = (const float*)d_in[15];
  float* ws  = (float*)d_ws;
  float* out = (float*)d_out;

  gru_kernel<<<256, 512, 0, stream>>>(x, Wih, projW, projb, bih, Whh, bhh, outW, ws);
  scoretopk_kernel<<<24, 512, 0, stream>>>(spaceW, spaceb, queries, routerW, routerb, ws, out);
  evfinal_kernel<<<64, 256, 0, stream>>>(prior, outb, plog, ws, out);
}

// Round 7
// 229.341 us; speedup vs baseline: 1.4140x; 1.4140x over previous
//
#include <hip/hip_runtime.h>
#include <math.h>

// Problem dims: B=8, N=512, T=64, D=128, E=32, M=3, BN=4096
// ws layout (float offsets)
#define OFF_QN     768        // 96*128 = 12288 normalized queries
#define OFF_H      13056      // 4096*128
#define OFF_HV     537376     // 4096
#define OFF_SCORES 541472     // 768*512
#define OFF_HMIX   934688     // 8*32*512 = 131072
#define OFF_SHI    1066016    // 24576 floats = 49152 bf16 (spaceW hi)
#define OFF_SLO    1090592    // 24576 floats (spaceW lo)
#define OFF_STATS  1115168    // 256 blocks * 256 floats (sum[128], sumsq[128])

typedef short bf16x8 __attribute__((ext_vector_type(8)));
typedef float f32x4 __attribute__((ext_vector_type(4)));

union U8 { unsigned short s[8]; bf16x8 v; uint4 u4; };

__device__ __forceinline__ unsigned short bf16_rtn(float f) {
  unsigned int u = __float_as_uint(f);
  return (unsigned short)((u + 0x7FFFu + ((u >> 16) & 1u)) >> 16);
}
__device__ __forceinline__ float bf16_f(unsigned short h) {
  return __uint_as_float(((unsigned int)h) << 16);
}
__device__ __forceinline__ void split8_rtn(const float* v, bf16x8* hi, bf16x8* lo) {
  U8 a, b;
#pragma unroll
  for (int j = 0; j < 8; ++j) {
    unsigned short h = bf16_rtn(v[j]);
    a.s[j] = h;
    b.s[j] = bf16_rtn(v[j] - bf16_f(h));
  }
  *hi = a.v; *lo = b.v;
}

// ---------------------------------------------------------------------------
// GRU: 256 blocks x 512 threads, 16 seqs/block. Self-contained, and absorbs
// all one-time prep: Hmix zero slice, spaceW bf16 hi/lo split, qn rows,
// and per-block stats partials (sum/sumsq of its 16 h rows).
// ---------------------------------------------------------------------------
__global__ __launch_bounds__(512, 2) void gru_kernel(const float* __restrict__ x,
                                                     const float* __restrict__ Wih,
                                                     const float* __restrict__ projW,
                                                     const float* __restrict__ projb,
                                                     const float* __restrict__ bih,
                                                     const float* __restrict__ Whh,
                                                     const float* __restrict__ bhh,
                                                     const float* __restrict__ outW,
                                                     const float* __restrict__ spaceW,
                                                     const float* __restrict__ queries,
                                                     float* __restrict__ ws) {
  __shared__ __align__(16) unsigned short hHi[2][16 * 17 * 8];
  __shared__ __align__(16) unsigned short hLo[2][16 * 17 * 8];
  __shared__ float xsAll[16 * 65];
  __shared__ float hFin[16 * 132];

  const int tid = threadIdx.x, wave = tid >> 6, lane = tid & 63;
  const int q = lane >> 4, s15 = lane & 15;
  const int d = wave * 16 + s15;

  // one-time prep, distributed over blocks
  {
    float4 z4 = make_float4(0.f, 0.f, 0.f, 0.f);
    float4* hm4 = (float4*)(ws + OFF_HMIX);
    if (tid < 128) hm4[blockIdx.x * 128 + tid] = z4;  // zero Hmix slice
    if (tid < 192) {                                   // spaceW split slice
      int i = blockIdx.x * 192 + tid;
      float w = spaceW[i];
      unsigned short hi = bf16_rtn(w);
      ((unsigned short*)(ws + OFF_SHI))[i] = hi;
      ((unsigned short*)(ws + OFF_SLO))[i] = bf16_rtn(w - bf16_f(hi));
    }
    if (blockIdx.x < 96 && wave == 1) {                // qn row
      const float* qrow = queries + blockIdx.x * 128;
      float v0 = qrow[lane], v1 = qrow[64 + lane];
      float ss = v0 * v0 + v1 * v1;
      for (int off = 32; off; off >>= 1) ss += __shfl_xor(ss, off);
      float inv = 1.f / fmaxf(sqrtf(ss), 1e-12f);
      ws[OFF_QN + blockIdx.x * 128 + lane] = v0 * inv;
      ws[OFF_QN + blockIdx.x * 128 + 64 + lane] = v1 * inv;
    }
  }

  // W_hh B-fragments (split bf16) from global fp32
  bf16x8 Bhi[3][4], Blo[3][4];
#pragma unroll
  for (int t = 0; t < 3; ++t) {
    int row = (wave + 8 * t) * 16 + s15;
#pragma unroll
    for (int c = 0; c < 4; ++c) {
      float v[8];
      *(float4*)v = *(const float4*)&Whh[row * 128 + c * 32 + q * 8];
      *(float4*)(v + 4) = *(const float4*)&Whh[row * 128 + c * 32 + q * 8 + 4];
      split8_rtn(v, &Bhi[t][c], &Blo[t][c]);
    }
  }

  // u/c per-lane constants
  float ur = 0.f, uz = 0.f, un = 0.f, pr0 = 0.f, pz0 = 0.f, pn0 = 0.f;
  for (int k = 0; k < 128; k += 4) {
    float4 w0 = *(const float4*)&Wih[d * 128 + k];
    float4 w1 = *(const float4*)&Wih[(128 + d) * 128 + k];
    float4 w2 = *(const float4*)&Wih[(256 + d) * 128 + k];
    float4 pw = *(const float4*)&projW[k];
    float4 pb = *(const float4*)&projb[k];
    ur += w0.x * pw.x + w0.y * pw.y + w0.z * pw.z + w0.w * pw.w;
    uz += w1.x * pw.x + w1.y * pw.y + w1.z * pw.z + w1.w * pw.w;
    un += w2.x * pw.x + w2.y * pw.y + w2.z * pw.z + w2.w * pw.w;
    pr0 += w0.x * pb.x + w0.y * pb.y + w0.z * pb.z + w0.w * pb.w;
    pz0 += w1.x * pb.x + w1.y * pb.y + w1.z * pb.z + w1.w * pb.w;
    pn0 += w2.x * pb.x + w2.y * pb.y + w2.z * pb.z + w2.w * pb.w;
  }
  const float cr = pr0 + bih[d] + bhh[d];
  const float cz = pz0 + bih[128 + d] + bhh[128 + d];
  const float cn = pn0 + bih[256 + d];
  const float bj2 = bhh[256 + d];

  const int seq0 = blockIdx.x * 16;
  for (int i = tid; i < 1024; i += 512) {
    int s = i >> 6, tt = i & 63;
    int r = (seq0 + s) * 64 + tt;
    xsAll[s * 65 + tt] = x[((r >> 15) * 512 + (r & 511)) * 64 + ((r >> 9) & 63)];
  }
  for (int i = tid; i < 2176; i += 512) { hHi[0][i] = 0; hLo[0][i] = 0; }
  __syncthreads();

  float hreg[4] = {0.f, 0.f, 0.f, 0.f};
  const int g = d >> 3, e = d & 7;

  for (int t = 0; t < 64; ++t) {
    const int rb = t & 1, wb = rb ^ 1;
    f32x4 acc0 = {0.f, 0.f, 0.f, 0.f};
    f32x4 acc1 = {0.f, 0.f, 0.f, 0.f};
    f32x4 acc2 = {0.f, 0.f, 0.f, 0.f};
#pragma unroll
    for (int c = 0; c < 4; ++c) {
      bf16x8 Ahi = *(const bf16x8*)&hHi[rb][((c * 4 + q) * 17 + s15) * 8];
      bf16x8 Alo = *(const bf16x8*)&hLo[rb][((c * 4 + q) * 17 + s15) * 8];
      acc0 = __builtin_amdgcn_mfma_f32_16x16x32_bf16(Ahi, Bhi[0][c], acc0, 0, 0, 0);
      acc1 = __builtin_amdgcn_mfma_f32_16x16x32_bf16(Ahi, Bhi[1][c], acc1, 0, 0, 0);
      acc2 = __builtin_amdgcn_mfma_f32_16x16x32_bf16(Ahi, Bhi[2][c], acc2, 0, 0, 0);
      acc0 = __builtin_amdgcn_mfma_f32_16x16x32_bf16(Alo, Bhi[0][c], acc0, 0, 0, 0);
      acc1 = __builtin_amdgcn_mfma_f32_16x16x32_bf16(Alo, Bhi[1][c], acc1, 0, 0, 0);
      acc2 = __builtin_amdgcn_mfma_f32_16x16x32_bf16(Alo, Bhi[2][c], acc2, 0, 0, 0);
      acc0 = __builtin_amdgcn_mfma_f32_16x16x32_bf16(Ahi, Blo[0][c], acc0, 0, 0, 0);
      acc1 = __builtin_amdgcn_mfma_f32_16x16x32_bf16(Ahi, Blo[1][c], acc1, 0, 0, 0);
      acc2 = __builtin_amdgcn_mfma_f32_16x16x32_bf16(Ahi, Blo[2][c], acc2, 0, 0, 0);
    }
    float xsv[4];
#pragma unroll
    for (int r = 0; r < 4; ++r) xsv[r] = xsAll[(q * 4 + r) * 65 + t];
#pragma unroll
    for (int r = 0; r < 4; ++r) {
      int s = q * 4 + r;
      float gr = fmaf(xsv[r], ur, cr + acc0[r]);
      float gz = fmaf(xsv[r], uz, cz + acc1[r]);
      float gn = fmaf(xsv[r], un, cn);
      float hn = acc2[r] + bj2;
      float rr = __builtin_amdgcn_rcpf(1.f + __expf(-gr));
      float zz = 1.f - __builtin_amdgcn_rcpf(1.f + __expf(-gz));  // 1-z
      float a = fmaf(rr, hn, gn);
      float ng = 1.f - 2.f * __builtin_amdgcn_rcpf(__expf(2.f * a) + 1.f);
      float hv = fmaf(zz, ng - hreg[r], hreg[r]);
      hreg[r] = hv;
      unsigned int u = __float_as_uint(hv);
      unsigned short hi = (unsigned short)(u >> 16);                 // trunc-hi
      unsigned short lo = bf16_rtn(hv - __uint_as_float(u & 0xFFFF0000u));
      int idx = (g * 17 + s) * 8 + e;
      hHi[wb][idx] = hi;
      hLo[wb][idx] = lo;
    }
    __syncthreads();
  }

  // final h -> LDS staging, then global + hv + stats partials
#pragma unroll
  for (int r = 0; r < 4; ++r) hFin[(q * 4 + r) * 132 + d] = hreg[r];
  __syncthreads();
  float* h_out = ws + OFF_H;
#pragma unroll
  for (int p = 0; p < 4; ++p) {
    int item = tid + p * 512;
    int s = item >> 7, dd = item & 127;
    h_out[(seq0 + s) * 128 + dd] = hFin[s * 132 + dd];
  }
  for (int s = wave * 2; s < wave * 2 + 2; ++s) {
    float a = hFin[s * 132 + lane] * outW[lane] + hFin[s * 132 + 64 + lane] * outW[64 + lane];
    for (int off = 32; off; off >>= 1) a += __shfl_xor(a, off);
    if (lane == 0) ws[OFF_HV + seq0 + s] = a;
  }
  if (tid < 128) {
    float s = 0.f, q2 = 0.f;
#pragma unroll
    for (int sI = 0; sI < 16; ++sI) {
      float v = hFin[sI * 132 + tid];
      s += v; q2 += v * v;
    }
    ws[OFF_STATS + blockIdx.x * 256 + tid] = s;
    ws[OFF_STATS + blockIdx.x * 256 + 128 + tid] = q2;
  }
}

// ---------------------------------------------------------------------------
// scores via split-bf16 MFMA (R5-verified). Grid 384 = (b,m,chunk of 32 n).
// ---------------------------------------------------------------------------
__global__ __launch_bounds__(256) void scores_kernel(const float* __restrict__ spaceb,
                                                     float* __restrict__ ws) {
  const int bid = blockIdx.x;
  const int chunk = bid & 15, m = (bid >> 4) % 3, b = bid / 48;
  const int n0 = chunk * 32;
  const int tid = threadIdx.x, wave = tid >> 6, lane = tid & 63;
  const int q = lane >> 4, s15 = lane & 15;

  __shared__ __align__(16) unsigned short sHi[16 * 33 * 8];
  __shared__ __align__(16) unsigned short sLo[16 * 33 * 8];
  __shared__ float hsL[32 * 132];
  __shared__ float biasL[128];
  __shared__ float invnL[32];

  const float* hG = ws + OFF_H;
  const unsigned short* SHI = (const unsigned short*)(ws + OFF_SHI);
  const unsigned short* SLO = (const unsigned short*)(ws + OFF_SLO);

  if (tid < 128) biasL[tid] = spaceb[m * 128 + tid];
  {
    int nn = tid >> 3, kc = tid & 7;
    const float* row = &hG[(b * 512 + n0 + nn) * 128 + kc * 16];
    U8 ph0, pl0, ph1, pl1;
#pragma unroll
    for (int j = 0; j < 8; ++j) {
      float v = row[j];
      unsigned short hi = bf16_rtn(v);
      ph0.s[j] = hi; pl0.s[j] = bf16_rtn(v - bf16_f(hi));
    }
#pragma unroll
    for (int j = 0; j < 8; ++j) {
      float v = row[8 + j];
      unsigned short hi = bf16_rtn(v);
      ph1.s[j] = hi; pl1.s[j] = bf16_rtn(v - bf16_f(hi));
    }
    int g0 = kc * 2;
    *(uint4*)&sHi[(g0 * 33 + nn) * 8] = ph0.u4;
    *(uint4*)&sLo[(g0 * 33 + nn) * 8] = pl0.u4;
    *(uint4*)&sHi[((g0 + 1) * 33 + nn) * 8] = ph1.u4;
    *(uint4*)&sLo[((g0 + 1) * 33 + nn) * 8] = pl1.u4;
  }
  __syncthreads();

  const int nt = wave >> 1;
  const int dt0 = (wave & 1) * 4;
  f32x4 acc[4] = {{0.f,0.f,0.f,0.f},{0.f,0.f,0.f,0.f},{0.f,0.f,0.f,0.f},{0.f,0.f,0.f,0.f}};
#pragma unroll
  for (int c = 0; c < 4; ++c) {
    bf16x8 Ahi = *(const bf16x8*)&sHi[((c * 4 + q) * 33 + nt * 16 + s15) * 8];
    bf16x8 Alo = *(const bf16x8*)&sLo[((c * 4 + q) * 33 + nt * 16 + s15) * 8];
#pragma unroll
    for (int i = 0; i < 4; ++i) {
      int row = m * 16384 + ((dt0 + i) * 16 + s15) * 128 + c * 32 + q * 8;
      bf16x8 Bhi = *(const bf16x8*)&SHI[row];
      bf16x8 Blo = *(const bf16x8*)&SLO[row];
      acc[i] = __builtin_amdgcn_mfma_f32_16x16x32_bf16(Ahi, Bhi, acc[i], 0, 0, 0);
      acc[i] = __builtin_amdgcn_mfma_f32_16x16x32_bf16(Alo, Bhi, acc[i], 0, 0, 0);
      acc[i] = __builtin_amdgcn_mfma_f32_16x16x32_bf16(Ahi, Blo, acc[i], 0, 0, 0);
    }
  }
#pragma unroll
  for (int i = 0; i < 4; ++i) {
    int dcol = (dt0 + i) * 16 + s15;
    float bb = biasL[dcol];
#pragma unroll
    for (int r = 0; r < 4; ++r)
      hsL[(nt * 16 + q * 4 + r) * 132 + dcol] = acc[i][r] + bb;
  }
  __syncthreads();

  {
    int n = tid >> 3, kc = tid & 7;
    float ss = 0.f;
#pragma unroll
    for (int d4 = 0; d4 < 4; ++d4) {
      float4 v = *(const float4*)&hsL[n * 132 + kc * 16 + d4 * 4];
      ss += v.x * v.x + v.y * v.y + v.z * v.z + v.w * v.w;
    }
    ss += __shfl_xor(ss, 1); ss += __shfl_xor(ss, 2); ss += __shfl_xor(ss, 4);
    if (kc == 0) invnL[n] = 1.f / fmaxf(sqrtf(ss), 1e-12f);
  }
  __syncthreads();

  {
    int n = tid & 31, eg = tid >> 5;
    const float* qn = ws + OFF_QN + (m * 32 + eg * 4) * 128;
    float a0 = 0.f, a1 = 0.f, a2 = 0.f, a3 = 0.f;
#pragma unroll
    for (int d4 = 0; d4 < 32; ++d4) {
      float4 hv = *(const float4*)&hsL[n * 132 + d4 * 4];
      float4 q0 = *(const float4*)&qn[d4 * 4];
      float4 q1 = *(const float4*)&qn[128 + d4 * 4];
      float4 q2 = *(const float4*)&qn[256 + d4 * 4];
      float4 q3 = *(const float4*)&qn[384 + d4 * 4];
      a0 += hv.x * q0.x + hv.y * q0.y + hv.z * q0.z + hv.w * q0.w;
      a1 += hv.x * q1.x + hv.y * q1.y + hv.z * q1.z + hv.w * q1.w;
      a2 += hv.x * q2.x + hv.y * q2.y + hv.z * q2.z + hv.w * q2.w;
      a3 += hv.x * q3.x + hv.y * q3.y + hv.z * q3.z + hv.w * q3.w;
    }
    float inv = invnL[n];
    float* sc = ws + OFF_SCORES + ((b * 3 + m) * 32 + eg * 4) * 512 + n0 + n;
    sc[0]    = a0 * inv;
    sc[512]  = a1 * inv;
    sc[1024] = a2 * inv;
    sc[1536] = a3 * inv;
  }
}

// ---------------------------------------------------------------------------
// topk: 192 blocks x 256. Block reduces stats partials -> router probs, then
// 4 wave-rows of top-25 + softmax + Hmix scatter.
// ---------------------------------------------------------------------------
__global__ __launch_bounds__(256) void topk_kernel(const float* __restrict__ routerW,
                                                   const float* __restrict__ routerb,
                                                   float* __restrict__ ws,
                                                   float* __restrict__ d_out) {
  const int row0 = blockIdx.x * 4;
  const int b = row0 / 96, m = (row0 / 32) % 3;
  const int tid = threadIdx.x, wave = tid >> 6, lane = tid & 63;
  __shared__ float st[256], lgS[3];
  __shared__ float probsS;

  if (tid < 128) {
    float s = 0.f, q2 = 0.f;
    const float* base = ws + OFF_STATS + b * 32 * 256;
    for (int j = 0; j < 32; ++j) {
      s += base[j * 256 + tid];
      q2 += base[j * 256 + 128 + tid];
    }
    float mean = s * (1.f / 512.f);
    float var = (q2 - 512.f * mean * mean) * (1.f / 511.f);  // ddof=1
    st[tid] = mean;
    st[128 + tid] = sqrtf(fmaxf(var, 0.f));
  }
  __syncthreads();
  if (tid < 3) {
    float acc = routerb[tid];
    for (int k = 0; k < 256; ++k) acc += st[k] * routerW[tid * 256 + k];
    lgS[tid] = acc;
  }
  __syncthreads();
  if (tid == 0) {
    float mx = fmaxf(lgS[0], fmaxf(lgS[1], lgS[2]));
    float e0 = expf(lgS[0] - mx), e1 = expf(lgS[1] - mx), e2 = expf(lgS[2] - mx);
    float inv = 1.f / (e0 + e1 + e2);
    probsS = (m == 0) ? e0 * inv : ((m == 1) ? e1 * inv : e2 * inv);
    if (m == 0 && (row0 % 96) == 0) {
      d_out[4096 + b * 3 + 0] = e0 * inv;
      d_out[4096 + b * 3 + 1] = e1 * inv;
      d_out[4096 + b * 3 + 2] = e2 * inv;
    }
  }
  __syncthreads();

  int row = row0 + wave;
  int e = row & 31;
  const float* sc = ws + OFF_SCORES + row * 512;
  float prob = probsS;

  float v[8];
#pragma unroll
  for (int j = 0; j < 8; ++j) v[j] = sc[j * 64 + lane];

  float selv = 0.f; int seli = 0; float maxv = 0.f;
  for (int it = 0; it < 25; ++it) {
    float bv = v[0]; int bj = 0;
#pragma unroll
    for (int j = 1; j < 8; ++j)
      if (v[j] > bv) { bv = v[j]; bj = j; }
    int bidx = bj * 64 + lane;
    for (int off = 32; off; off >>= 1) {
      float ov = __shfl_xor(bv, off);
      int oi = __shfl_xor(bidx, off);
      if (ov > bv || (ov == bv && oi < bidx)) { bv = ov; bidx = oi; }
    }
    if (lane == (bidx & 63)) v[bidx >> 6] = -INFINITY;
    if (it == 0) maxv = bv;
    if (lane == it) { selv = bv; seli = bidx; }
  }
  float ex = (lane < 25) ? __expf((selv - maxv) * (1.f / 0.7f)) : 0.f;
  float den = ex;
  for (int off = 32; off; off >>= 1) den += __shfl_xor(den, off);
  if (lane < 25)
    atomicAdd(&ws[OFF_HMIX + (b * 32 + e) * 512 + seli], prob * ex / den);
}

// ---------------------------------------------------------------------------
// ev + final fused: 64 blocks (b, 64-n chunk) x 512 threads.
// ---------------------------------------------------------------------------
__global__ __launch_bounds__(512) void evfinal_kernel(const float* __restrict__ prior,
                                                      const float* __restrict__ outb,
                                                      const float* __restrict__ plog,
                                                      float* __restrict__ ws,
                                                      float* __restrict__ d_out) {
  const int bid = blockIdx.x;
  const int b = bid >> 3, ch = bid & 7;
  const int tid = threadIdx.x, wave = tid >> 6, lane = tid & 63;
  __shared__ float hvL[512], evL[32];
  hvL[tid] = ws[OFF_HV + b * 512 + tid];
  __syncthreads();
#pragma unroll
  for (int i = 0; i < 4; ++i) {
    int e = wave * 4 + i;
    const float* Hm = ws + OFF_HMIX + (b * 32 + e) * 512;
    float a = 0.f;
#pragma unroll
    for (int j = 0; j < 8; ++j) a += Hm[j * 64 + lane] * hvL[j * 64 + lane];
    for (int off = 32; off; off >>= 1) a += __shfl_xor(a, off);
    if (lane == 0) evL[e] = a;
  }
  __syncthreads();
  float alpha = 1.f / (1.f + expf(-plog[0]));
  float ob = outb[0];
#pragma unroll
  for (int i = 0; i < 8; ++i) {
    int n = ch * 64 + wave * 8 + i;
    const float* pr = prior + n * 512;
    float s1 = 0.f;
#pragma unroll
    for (int j = 0; j < 8; ++j) s1 += pr[j * 64 + lane] * hvL[j * 64 + lane];
    float s2 = 0.f;
    if (lane < 32) s2 = ws[OFF_HMIX + (b * 32 + lane) * 512 + n] * evL[lane];
    float a = alpha * s1 + (1.f - alpha) * s2;
    for (int off = 32; off; off >>= 1) a += __shfl_xor(a, off);
    if (lane == 0) d_out[b * 512 + n] = a + ob;
  }
}

// ---------------------------------------------------------------------------
extern "C" void kernel_launch(void* const* d_in, const int* in_sizes, int n_in,
                              void* d_out, int out_size, void* d_ws, size_t ws_size,
                              hipStream_t stream) {
  const float* x       = (const float*)d_in[0];
  const float* prior   = (const float*)d_in[1];
  const float* projW   = (const float*)d_in[2];
  const float* projb   = (const float*)d_in[3];
  const float* Wih     = (const float*)d_in[4];
  const float* Whh     = (const float*)d_in[5];
  const float* bih     = (const float*)d_in[6];
  const float* bhh     = (const float*)d_in[7];
  const float* spaceW  = (const float*)d_in[8];
  const float* spaceb  = (const float*)d_in[9];
  const float* routerW = (const float*)d_in[10];
  const float* routerb = (const float*)d_in[11];
  const float* outW    = (const float*)d_in[12];
  const float* outb    = (const float*)d_in[13];
  const float* plog    = (const float*)d_in[14];
  const float* queries = (const float*)d_in[15];
  float* ws  = (float*)d_ws;
  float* out = (float*)d_out;

  gru_kernel<<<256, 512, 0, stream>>>(x, Wih, projW, projb, bih, Whh, bhh, outW,
                                      spaceW, queries, ws);
  scores_kernel<<<384, 256, 0, stream>>>(spaceb, ws);
  topk_kernel<<<192, 256, 0, stream>>>(routerW, routerb, ws, out);
  evfinal_kernel<<<64, 512, 0, stream>>>(prior, outb, plog, ws, out);
}